// Round 7
// baseline (439.523 us; speedup 1.0000x reference)
//
#include <hip/hip_runtime.h>
#include <hip/hip_bf16.h>
#include <stdint.h>

#define B_SZ 4
#define T_LEN 8192
#define D_DIM 512
#define M_TOT 32768
#define CHUNK 128
#define NCH 64    // chunks per batch
#define SCS 132   // f32 scan-tile LDS stride: 2-way max (free)

typedef __attribute__((ext_vector_type(8))) short bf16x8v;
typedef __attribute__((ext_vector_type(4))) float f32x4v;

__device__ __forceinline__ unsigned short f2bf(float f) {
  unsigned int u = __float_as_uint(f);
  u += 0x7fffu + ((u >> 16) & 1u);
  return (unsigned short)(u >> 16);
}
__device__ __forceinline__ float bf2f(unsigned short b) {
  return __uint_as_float(((unsigned int)b) << 16);
}
__device__ __forceinline__ float sigmoidf_(float x) { return 1.0f / (1.0f + expf(-x)); }

// ---------------------------------------------------------------------------
// prep: blocks 0..1023 -> Wb,Wc to bf16 | block 1024 -> powA[i][ch]=a^(i+1)
__global__ void prep_k(const float* __restrict__ Wb, const float* __restrict__ Wc,
                       const float* __restrict__ A, unsigned short* __restrict__ wbf,
                       float* __restrict__ powA) {
  const int b = blockIdx.x;
  const int tid = threadIdx.x;
  if (b < 1024) {
    int i = b * 256 + tid;
    wbf[i] = f2bf(Wb[i]);
    wbf[262144 + i] = f2bf(Wc[i]);
  } else {
#pragma unroll
    for (int s = 0; s < 2; ++s) {
      int ch = s * 256 + tid;
      float a = sigmoidf_(A[ch]);
      float p = a;
      for (int i = 0; i < CHUNK; ++i) {
        powA[i * D_DIM + ch] = p;
        p *= a;
      }
    }
  }
}

// ---------------------------------------------------------------------------
// In-place chunk-carry prefix. grid=B_SZ, block=512.
__global__ void carry_k(const float* __restrict__ A, float* __restrict__ cst) {
  const int ch = threadIdx.x;
  const int bi = blockIdx.x;
  float a = sigmoidf_(A[ch]);
  float p = a;
#pragma unroll
  for (int i = 0; i < 7; ++i) p *= p;  // a^128
  float H = 0.f;
#pragma unroll 8
  for (int c = 0; c < NCH; ++c) {
    size_t off = ((size_t)bi * NCH + c) * D_DIM + ch;
    float lf = cst[off];
    cst[off] = H;
    H = fmaf(p, H, lf);
  }
}

// ---------------------------------------------------------------------------
// 128x128xBK64 bf16 GEMM. Reg-staged with two-sided XOR swizzle (r1 pattern,
// 0 bank conflicts measured) + T14 async split: issue global loads (t+1) at
// step start -> ds_read frags (t) -> lgkm drain + barrier (WAR) -> MFMA ->
// vmcnt(0) -> ds_write (t+1) -> lgkm drain + barrier (RAW). Single 32KB buf.
// MODE 0: A = x (f32), converted during staging; epilogue = fused chunk scan
//         -> h_local bf16 + chunk finals. C unused.
// MODE 1: A = h_local bf16 with carry fix (powA*cst) applied in staging;
//         epilogue = per-wave LDS-transposed coalesced f32 C store.
template <int MODE>
__global__ __launch_bounds__(256, 3) void gemm_k(
    const void* __restrict__ Aptr, const unsigned short* __restrict__ Bw,
    float* __restrict__ C, const float* __restrict__ Ad,
    unsigned short* __restrict__ hOut, float* __restrict__ cst,
    const float* __restrict__ powA) {
  __shared__ union {
    unsigned short st[2][8192];  // [A,B][128*64] bf16, XOR-swizzled (32 KB)
    float sc[64 * SCS];          // MODE0 scan half-tile (33.8 KB)
    float tp[4][16 * 68];        // MODE1 per-wave transpose
  } sm;

  const int tid = threadIdx.x;
  const int lane = tid & 63;
  const int w = tid >> 6;
  const int wm = (w >> 1) * 64;
  const int wn = (w & 1) * 64;

  // bijective XCD swizzle (grid 1024 = 8*128), n-major within XCD
  const int flat = blockIdx.y * 4 + blockIdx.x;
  const int work = ((flat & 7) << 7) | (flat >> 3);
  const int mt = work >> 2;
  const int bm = mt * 128;
  const int bn = (work & 3) * 128;

  const int l15 = lane & 15;
  const int g4 = lane >> 4;
  const int r16 = tid >> 4, u16 = tid & 15;  // f32 staging coords
  const int r0 = tid >> 3, u8 = tid & 7;     // bf16 staging coords

  float4 aF[8];  // MODE0 prefetch (f32 x-tile)
  uint4 aH[4];   // MODE1 prefetch (bf16 h-tile)
  uint4 bS[4];   // B prefetch

  auto loadG = [&](int k0) {
    if constexpr (MODE == 0) {
      const float* Ax = (const float*)Aptr;
#pragma unroll
      for (int it = 0; it < 8; ++it)
        aF[it] = *(const float4*)&Ax[(size_t)(bm + it * 16 + r16) * 512 + k0 + u16 * 4];
    } else {
      const unsigned short* Ah = (const unsigned short*)Aptr;
#pragma unroll
      for (int it = 0; it < 4; ++it)
        aH[it] = *(const uint4*)&Ah[(size_t)(bm + it * 32 + r0) * 512 + k0 + u8 * 8];
    }
#pragma unroll
    for (int it = 0; it < 4; ++it)
      bS[it] = *(const uint4*)&Bw[(size_t)(bn + it * 32 + r0) * 512 + k0 + u8 * 8];
  };

  auto writeS = [&](int k0) {
    if constexpr (MODE == 0) {
#pragma unroll
      for (int it = 0; it < 8; ++it) {
        int row = it * 16 + r16;
        float4 v = aF[it];
        unsigned lo = (unsigned)f2bf(v.x) | ((unsigned)f2bf(v.y) << 16);
        unsigned hi = (unsigned)f2bf(v.z) | ((unsigned)f2bf(v.w) << 16);
        int byte = (row * 128 + u16 * 8) ^ ((row & 7) << 4);
        *(uint2*)((char*)sm.st[0] + byte) = make_uint2(lo, hi);
      }
    } else {
      float cr[8];
      *(float4*)cr = *(const float4*)&cst[(size_t)mt * D_DIM + k0 + u8 * 8];
      *(float4*)(cr + 4) = *(const float4*)&cst[(size_t)mt * D_DIM + k0 + u8 * 8 + 4];
#pragma unroll
      for (int it = 0; it < 4; ++it) {
        int row = it * 32 + r0;
        float pr[8];
        *(float4*)pr = *(const float4*)&powA[row * D_DIM + k0 + u8 * 8];
        *(float4*)(pr + 4) = *(const float4*)&powA[row * D_DIM + k0 + u8 * 8 + 4];
        const unsigned* hw = (const unsigned*)&aH[it];
        unsigned wv[4];
#pragma unroll
        for (int q = 0; q < 4; ++q) {
          float o0 = fmaf(pr[2 * q], cr[2 * q], bf2f((unsigned short)(hw[q] & 0xffff)));
          float o1 = fmaf(pr[2 * q + 1], cr[2 * q + 1], bf2f((unsigned short)(hw[q] >> 16)));
          wv[q] = (unsigned)f2bf(o0) | ((unsigned)f2bf(o1) << 16);
        }
        int byte = (row * 128 + u8 * 16) ^ ((row & 7) << 4);
        *(uint4*)((char*)sm.st[0] + byte) = make_uint4(wv[0], wv[1], wv[2], wv[3]);
      }
    }
#pragma unroll
    for (int it = 0; it < 4; ++it) {
      int row = it * 32 + r0;
      int byte = (row * 128 + u8 * 16) ^ ((row & 7) << 4);
      *(uint4*)((char*)sm.st[1] + byte) = bS[it];
    }
  };

  f32x4v acc[4][4] = {};

  // prologue: stage tile 0
  loadG(0);
  asm volatile("s_waitcnt vmcnt(0)" ::: "memory");
  writeS(0);
  asm volatile("s_waitcnt lgkmcnt(0)" ::: "memory");
  __builtin_amdgcn_s_barrier();

#pragma unroll
  for (int t = 0; t < 8; ++t) {
    if (t < 7) loadG((t + 1) * 64);  // issue next tile -> regs (flies under B+C)
    // frag reads of tile t
    bf16x8v af[4][2], bf_[4][2];
#pragma unroll
    for (int ks = 0; ks < 2; ++ks) {
#pragma unroll
      for (int i = 0; i < 4; ++i) {
        int row = wm + i * 16 + l15;
        int byte = (row * 128 + ks * 64 + g4 * 16) ^ ((row & 7) << 4);
        af[i][ks] = *(const bf16x8v*)((const char*)sm.st[0] + byte);
      }
#pragma unroll
      for (int j = 0; j < 4; ++j) {
        int row = wn + j * 16 + l15;
        int byte = (row * 128 + ks * 64 + g4 * 16) ^ ((row & 7) << 4);
        bf_[j][ks] = *(const bf16x8v*)((const char*)sm.st[1] + byte);
      }
    }
    asm volatile("s_waitcnt lgkmcnt(0)" ::: "memory");
    __builtin_amdgcn_sched_barrier(0);  // rule 18: pin MFMA after lgkm drain
    __builtin_amdgcn_s_barrier();       // all waves done reading -> buf free (WAR)
    __builtin_amdgcn_s_setprio(1);
#pragma unroll
    for (int ks = 0; ks < 2; ++ks)
#pragma unroll
      for (int i = 0; i < 4; ++i)
#pragma unroll
        for (int j = 0; j < 4; ++j)
          acc[i][j] =
              __builtin_amdgcn_mfma_f32_16x16x32_bf16(af[i][ks], bf_[j][ks], acc[i][j], 0, 0, 0);
    __builtin_amdgcn_s_setprio(0);
    if (t < 7) {
      asm volatile("s_waitcnt vmcnt(0)" ::: "memory");  // tile t+1 regs landed
      writeS((t + 1) * 64);
      asm volatile("s_waitcnt lgkmcnt(0)" ::: "memory");  // writes committed
      __builtin_amdgcn_s_barrier();                       // RAW for next step
    }
  }

  if constexpr (MODE == 0) {
    // fused chunk-local scan, two 64-row halves
    float a = 0.f, hcar = 0.f;
    if (tid < 128) a = sigmoidf_(Ad[bn + tid]);
#pragma unroll
    for (int half = 0; half < 2; ++half) {
      if ((w >> 1) == half) {
#pragma unroll
        for (int i = 0; i < 4; ++i)
#pragma unroll
          for (int j = 0; j < 4; ++j)
#pragma unroll
            for (int r = 0; r < 4; ++r)
              sm.sc[(i * 16 + g4 * 4 + r) * SCS + wn + j * 16 + l15] = acc[i][j][r];
      }
      __syncthreads();
      if (tid < 128) {
        float h = hcar;
#pragma unroll 8
        for (int t = 0; t < 64; ++t) {
          h = fmaf(a, h, sm.sc[t * SCS + tid]);
          sm.sc[t * SCS + tid] = h;
        }
        hcar = h;
      }
      __syncthreads();
#pragma unroll
      for (int p = 0; p < 4; ++p) {
        int uu = p * 256 + tid;
        int row = uu >> 4, c8 = (uu & 15) * 8;
        const float* s = &sm.sc[row * SCS + c8];
        unsigned w0 = (unsigned)f2bf(s[0]) | ((unsigned)f2bf(s[1]) << 16);
        unsigned w1 = (unsigned)f2bf(s[2]) | ((unsigned)f2bf(s[3]) << 16);
        unsigned w2 = (unsigned)f2bf(s[4]) | ((unsigned)f2bf(s[5]) << 16);
        unsigned w3 = (unsigned)f2bf(s[6]) | ((unsigned)f2bf(s[7]) << 16);
        *(uint4*)&hOut[(size_t)(bm + half * 64 + row) * D_DIM + bn + c8] =
            make_uint4(w0, w1, w2, w3);
      }
      __syncthreads();
    }
    if (tid < 128) cst[(size_t)mt * D_DIM + bn + tid] = hcar;
  } else {
    // coalesced C store via per-wave LDS transpose
    float* tp = sm.tp[w];
#pragma unroll
    for (int i = 0; i < 4; ++i) {
#pragma unroll
      for (int j = 0; j < 4; ++j)
#pragma unroll
        for (int r = 0; r < 4; ++r)
          tp[(g4 * 4 + r) * 68 + j * 16 + l15] = acc[i][j][r];
#pragma unroll
      for (int p = 0; p < 4; ++p) {
        f32x4v v = *(const f32x4v*)&tp[(p * 4 + g4) * 68 + l15 * 4];
        *(f32x4v*)&C[(size_t)(bm + wm + i * 16 + p * 4 + g4) * 512 + bn + wn + l15 * 4] = v;
      }
    }
  }
}

// ---------------------------------------------------------------------------
extern "C" void kernel_launch(void* const* d_in, const int* in_sizes, int n_in,
                              void* d_out, int out_size, void* d_ws, size_t ws_size,
                              hipStream_t stream) {
  const float* x = (const float*)d_in[0];
  const float* W_B = (const float*)d_in[1];
  const float* W_C = (const float*)d_in[2];
  const float* A = (const float*)d_in[3];
  float* out = (float*)d_out;
  char* ws = (char*)d_ws;

  // ws: [0,512K) Wb | [512K,1M) Wc | [1M,1.25M) powA | [1.25M,1.75M) cst |
  //     [2M,34M) h_local bf16
  unsigned short* Wb = (unsigned short*)ws;
  unsigned short* Wc = Wb + 262144;
  float* powA = (float*)(ws + 0x100000);
  float* cst = (float*)(ws + 0x140000);
  unsigned short* hbf = (unsigned short*)(ws + 0x200000);

  prep_k<<<1025, 256, 0, stream>>>(W_B, W_C, A, Wb, powA);

  dim3 gg(D_DIM / 128, M_TOT / 128);  // (4, 256)
  gemm_k<0><<<gg, 256, 0, stream>>>(x, Wb, nullptr, A, hbf, cst, powA);
  carry_k<<<B_SZ, 512, 0, stream>>>(A, cst);
  gemm_k<1><<<gg, 256, 0, stream>>>(hbf, Wc, out, A, nullptr, cst, powA);
}

// Round 8
// 127.587 us; speedup vs baseline: 3.4449x; 3.4449x over previous
//
#include <hip/hip_runtime.h>
#include <hip/hip_bf16.h>
#include <stdint.h>

#define B_SZ 4
#define T_LEN 8192
#define D_DIM 512
#define M_TOT 32768
#define CHUNK 128
#define NCH 64    // chunks per batch
#define SCS 132   // f32 scan-tile LDS stride: 2-way max (free)

typedef __attribute__((ext_vector_type(8))) short bf16x8v;
typedef __attribute__((ext_vector_type(4))) float f32x4v;

__device__ __forceinline__ unsigned short f2bf(float f) {
  unsigned int u = __float_as_uint(f);
  u += 0x7fffu + ((u >> 16) & 1u);
  return (unsigned short)(u >> 16);
}
__device__ __forceinline__ float bf2f(unsigned short b) {
  return __uint_as_float(((unsigned int)b) << 16);
}
__device__ __forceinline__ float sigmoidf_(float x) { return 1.0f / (1.0f + expf(-x)); }

// async global->LDS, 16B/lane; LDS dest = wave-uniform base + lane*16 (linear)
__device__ __forceinline__ void g2l16(const void* g, void* l) {
  __builtin_amdgcn_global_load_lds((const __attribute__((address_space(1))) void*)g,
                                   (__attribute__((address_space(3))) void*)l, 16, 0, 0);
}

// ---------------------------------------------------------------------------
// prep: blocks 0..1023 -> Wb,Wc to bf16 | block 1024 -> powA[i][ch]=a^(i+1)
//       blocks 1025.. -> x (f32) to bf16 (into d_out scratch region)
__global__ void prep_k(const float* __restrict__ x, const float* __restrict__ Wb,
                       const float* __restrict__ Wc, const float* __restrict__ A,
                       unsigned short* __restrict__ wbf, float* __restrict__ powA,
                       unsigned short* __restrict__ xbf) {
  const int b = blockIdx.x;
  const int tid = threadIdx.x;
  if (b < 1024) {
    int i = b * 256 + tid;
    wbf[i] = f2bf(Wb[i]);
    wbf[262144 + i] = f2bf(Wc[i]);
  } else if (b == 1024) {
#pragma unroll
    for (int s = 0; s < 2; ++s) {
      int ch = s * 256 + tid;
      float a = sigmoidf_(A[ch]);
      float p = a;
      for (int i = 0; i < CHUNK; ++i) {
        powA[i * D_DIM + ch] = p;
        p *= a;
      }
    }
  } else {
    size_t idx = ((size_t)(b - 1025) * 256 + tid) * 8;
    float4 v0 = *(const float4*)&x[idx];
    float4 v1 = *(const float4*)&x[idx + 4];
    uint4 o;
    o.x = (unsigned)f2bf(v0.x) | ((unsigned)f2bf(v0.y) << 16);
    o.y = (unsigned)f2bf(v0.z) | ((unsigned)f2bf(v0.w) << 16);
    o.z = (unsigned)f2bf(v1.x) | ((unsigned)f2bf(v1.y) << 16);
    o.w = (unsigned)f2bf(v1.z) | ((unsigned)f2bf(v1.w) << 16);
    *(uint4*)&xbf[idx] = o;
  }
}

// ---------------------------------------------------------------------------
// In-place chunk-carry prefix. grid=B_SZ, block=512.
__global__ void carry_k(const float* __restrict__ A, float* __restrict__ cst) {
  const int ch = threadIdx.x;
  const int bi = blockIdx.x;
  float a = sigmoidf_(A[ch]);
  float p = a;
#pragma unroll
  for (int i = 0; i < 7; ++i) p *= p;  // a^128
  float H = 0.f;
#pragma unroll 8
  for (int c = 0; c < NCH; ++c) {
    size_t off = ((size_t)bi * NCH + c) * D_DIM + ch;
    float lf = cst[off];
    cst[off] = H;
    H = fmaf(p, H, lf);
  }
}

// ---------------------------------------------------------------------------
// fix: h[g*128+t][ch] += powA[t][ch] * carry[g][ch], in place (bf16).
__global__ void fix_k(unsigned short* __restrict__ h, const float* __restrict__ cst,
                      const float* __restrict__ powA) {
  const int g = blockIdx.x;
  const int u = threadIdx.x & 63;
  const int rs = threadIdx.x >> 6;
  float car[8];
  *(float4*)car = *(const float4*)&cst[(size_t)g * D_DIM + u * 8];
  *(float4*)(car + 4) = *(const float4*)&cst[(size_t)g * D_DIM + u * 8 + 4];
#pragma unroll
  for (int p = 0; p < 16; ++p) {
    int row = p * 8 + rs;
    size_t off = ((size_t)g * CHUNK + row) * D_DIM + u * 8;
    uint4 hv = *(const uint4*)&h[off];
    float4 p0 = *(const float4*)&powA[row * D_DIM + u * 8];
    float4 p1 = *(const float4*)&powA[row * D_DIM + u * 8 + 4];
    const unsigned* hw = (const unsigned*)&hv;
    unsigned ow[4];
#pragma unroll
    for (int q = 0; q < 4; ++q) {
      float pa = (q < 2) ? ((q == 0) ? p0.x : p0.z) : ((q == 2) ? p1.x : p1.z);
      float pb = (q < 2) ? ((q == 0) ? p0.y : p0.w) : ((q == 2) ? p1.y : p1.w);
      float o0 = fmaf(pa, car[2 * q], bf2f((unsigned short)(hw[q] & 0xffff)));
      float o1 = fmaf(pb, car[2 * q + 1], bf2f((unsigned short)(hw[q] >> 16)));
      ow[q] = (unsigned)f2bf(o0) | ((unsigned)f2bf(o1) << 16);
    }
    *(uint4*)&h[off] = make_uint4(ow[0], ow[1], ow[2], ow[3]);
  }
}

// ---------------------------------------------------------------------------
// 128x128xBK64 bf16 GEMM; gload_lds staging with LINEAR row-major LDS and
// PRE-SWIZZLED per-lane global source (m173 / rule #21): lane l reads row
// seg*8+(l>>3), k-chunk (l&7)^(l>>3) -> LDS image is XOR-swizzled. Staging
// writes hit banks 0..31 once per 8 lanes (0 conflicts); frag reads use the
// r1-validated XOR pattern (0 conflicts). Counted-vmcnt double buffer (r6
// race ledger carries over verbatim).
// MODE 0: epilogue = fused chunk scan -> h_local bf16 + chunk finals.
// MODE 1: epilogue = per-wave LDS-transposed coalesced f32 C store.
template <int MODE>
__global__ __launch_bounds__(256, 2) void gemm_k(
    const unsigned short* __restrict__ Abf, const unsigned short* __restrict__ Bw,
    float* __restrict__ C, const float* __restrict__ Ad,
    unsigned short* __restrict__ hOut, float* __restrict__ cst) {
  __shared__ union {
    unsigned short st[2][2][8192];  // [buf][A,B][128*64] bf16 (64 KB)
    float sc[64 * SCS];             // MODE0 scan half-tile (33.8 KB)
    float tp[4][16 * 68];           // MODE1 per-wave transpose
  } sm;

  const int tid = threadIdx.x;
  const int lane = tid & 63;
  const int w = tid >> 6;
  const int wm = (w >> 1) * 64;
  const int wn = (w & 1) * 64;

  // bijective XCD swizzle (grid 1024 = 8*128), n-major within XCD
  const int flat = blockIdx.y * 4 + blockIdx.x;
  const int work = ((flat & 7) << 7) | (flat >> 3);
  const int mt = work >> 2;
  const int bm = mt * 128;
  const int bn = (work & 3) * 128;

  const int l15 = lane & 15;
  const int g4 = lane >> 4;
  const int lrow = lane >> 3;              // row within 8-row segment
  const int lk = ((lane & 7) ^ lrow) * 8;  // pre-swizzled k-element offset

  // per-lane pre-swizzled global sources; wave w stages segments w*4..w*4+3
  const unsigned short* aSrc[4];
  const unsigned short* bSrc[4];
#pragma unroll
  for (int q = 0; q < 4; ++q) {
    int seg = w * 4 + q;
    aSrc[q] = Abf + (size_t)(bm + seg * 8 + lrow) * 512 + lk;
    bSrc[q] = Bw + (size_t)(bn + seg * 8 + lrow) * 512 + lk;
  }

  auto stage = [&](int buf, int k0) {
#pragma unroll
    for (int q = 0; q < 4; ++q) {
      int seg = w * 4 + q;  // wave-uniform LDS segment
      g2l16(aSrc[q] + k0, &sm.st[buf][0][seg * 512]);
      g2l16(bSrc[q] + k0, &sm.st[buf][1][seg * 512]);
    }
  };

  f32x4v acc[4][4] = {};

  // prologue: fill both buffers; wait only for buf0 (8 newest stay in flight)
  stage(0, 0);
  stage(1, 64);
  asm volatile("s_waitcnt vmcnt(8)" ::: "memory");
  __builtin_amdgcn_s_barrier();

#pragma unroll
  for (int t = 0; t < 8; ++t) {
    const int cur = t & 1;
    // #1 read all 16 fragments of buf[cur] (XOR-swizzled addresses)
    bf16x8v af[4][2], bf_[4][2];
#pragma unroll
    for (int ks = 0; ks < 2; ++ks) {
#pragma unroll
      for (int i = 0; i < 4; ++i) {
        int row = wm + i * 16 + l15;
        int byte = (row * 128 + ks * 64 + g4 * 16) ^ ((row & 7) << 4);
        af[i][ks] = *(const bf16x8v*)((const char*)sm.st[cur][0] + byte);
      }
#pragma unroll
      for (int j = 0; j < 4; ++j) {
        int row = wn + j * 16 + l15;
        int byte = (row * 128 + ks * 64 + g4 * 16) ^ ((row & 7) << 4);
        bf_[j][ks] = *(const bf16x8v*)((const char*)sm.st[cur][1] + byte);
      }
    }
    // #2 own reads landed; #3 all waves' reads landed (WAR gate)
    asm volatile("s_waitcnt lgkmcnt(0)" ::: "memory");
    __builtin_amdgcn_sched_barrier(0);
    __builtin_amdgcn_s_barrier();
    // #4 restage just-read buffer with tile t+2 (loads fly through next step)
    if (t < 6) stage(cur, (t + 2) * 64);
    // #5 MFMA cluster
    __builtin_amdgcn_s_setprio(1);
#pragma unroll
    for (int ks = 0; ks < 2; ++ks)
#pragma unroll
      for (int i = 0; i < 4; ++i)
#pragma unroll
        for (int j = 0; j < 4; ++j)
          acc[i][j] =
              __builtin_amdgcn_mfma_f32_16x16x32_bf16(af[i][ks], bf_[j][ks], acc[i][j], 0, 0, 0);
    __builtin_amdgcn_s_setprio(0);
    // #6 make buf[cur^1] ready: counted wait (8 newest = our restage stay out)
    if (t < 6) {
      asm volatile("s_waitcnt vmcnt(8)" ::: "memory");
      __builtin_amdgcn_s_barrier();
    } else if (t == 6) {
      asm volatile("s_waitcnt vmcnt(0)" ::: "memory");
      __builtin_amdgcn_s_barrier();
    }
  }

  if constexpr (MODE == 0) {
    // fused chunk-local scan, two 64-row halves
    float a = 0.f, hcar = 0.f;
    if (tid < 128) a = sigmoidf_(Ad[bn + tid]);
#pragma unroll
    for (int half = 0; half < 2; ++half) {
      if ((w >> 1) == half) {
#pragma unroll
        for (int i = 0; i < 4; ++i)
#pragma unroll
          for (int j = 0; j < 4; ++j)
#pragma unroll
            for (int r = 0; r < 4; ++r)
              sm.sc[(i * 16 + g4 * 4 + r) * SCS + wn + j * 16 + l15] = acc[i][j][r];
      }
      __syncthreads();
      if (tid < 128) {
        float h = hcar;
#pragma unroll 8
        for (int t = 0; t < 64; ++t) {
          h = fmaf(a, h, sm.sc[t * SCS + tid]);
          sm.sc[t * SCS + tid] = h;
        }
        hcar = h;
      }
      __syncthreads();
#pragma unroll
      for (int p = 0; p < 4; ++p) {
        int uu = p * 256 + tid;
        int row = uu >> 4, c8 = (uu & 15) * 8;
        const float* s = &sm.sc[row * SCS + c8];
        unsigned w0 = (unsigned)f2bf(s[0]) | ((unsigned)f2bf(s[1]) << 16);
        unsigned w1 = (unsigned)f2bf(s[2]) | ((unsigned)f2bf(s[3]) << 16);
        unsigned w2 = (unsigned)f2bf(s[4]) | ((unsigned)f2bf(s[5]) << 16);
        unsigned w3 = (unsigned)f2bf(s[6]) | ((unsigned)f2bf(s[7]) << 16);
        *(uint4*)&hOut[(size_t)(bm + half * 64 + row) * D_DIM + bn + c8] =
            make_uint4(w0, w1, w2, w3);
      }
      __syncthreads();
    }
    if (tid < 128) cst[(size_t)mt * D_DIM + bn + tid] = hcar;
  } else {
    // coalesced C store via per-wave LDS transpose
    float* tp = sm.tp[w];
#pragma unroll
    for (int i = 0; i < 4; ++i) {
#pragma unroll
      for (int j = 0; j < 4; ++j)
#pragma unroll
        for (int r = 0; r < 4; ++r)
          tp[(g4 * 4 + r) * 68 + j * 16 + l15] = acc[i][j][r];
#pragma unroll
      for (int p = 0; p < 4; ++p) {
        f32x4v v = *(const f32x4v*)&tp[(p * 4 + g4) * 68 + l15 * 4];
        *(f32x4v*)&C[(size_t)(bm + wm + i * 16 + p * 4 + g4) * 512 + bn + wn + l15 * 4] = v;
      }
    }
  }
}

// ---------------------------------------------------------------------------
extern "C" void kernel_launch(void* const* d_in, const int* in_sizes, int n_in,
                              void* d_out, int out_size, void* d_ws, size_t ws_size,
                              hipStream_t stream) {
  const float* x = (const float*)d_in[0];
  const float* W_B = (const float*)d_in[1];
  const float* W_C = (const float*)d_in[2];
  const float* A = (const float*)d_in[3];
  float* out = (float*)d_out;
  char* ws = (char*)d_ws;

  // ws: [0,512K) Wb | [512K,1M) Wc | [1M,1.25M) powA | [1.25M,1.75M) cst |
  //     [2M,34M) h_local bf16.  x_bf16 lives in d_out (dead before GEMM2's C-write).
  unsigned short* Wb = (unsigned short*)ws;
  unsigned short* Wc = Wb + 262144;
  float* powA = (float*)(ws + 0x100000);
  float* cst = (float*)(ws + 0x140000);
  unsigned short* hbf = (unsigned short*)(ws + 0x200000);
  unsigned short* xbf = (unsigned short*)d_out;

  prep_k<<<1025 + 8192, 256, 0, stream>>>(x, W_B, W_C, A, Wb, powA, xbf);

  dim3 gg(D_DIM / 128, M_TOT / 128);  // (4, 256)
  gemm_k<0><<<gg, 256, 0, stream>>>(xbf, Wb, nullptr, A, hbf, cst);
  carry_k<<<B_SZ, 512, 0, stream>>>(A, cst);
  fix_k<<<256, 512, 0, stream>>>(hbf, cst, powA);
  gemm_k<1><<<gg, 256, 0, stream>>>(hbf, Wc, out, A, nullptr, cst);
}